// Round 8
// baseline (173.645 us; speedup 1.0000x reference)
//
#include <hip/hip_runtime.h>
#include <math.h>

typedef _Float16 h16;
typedef _Float16 half8 __attribute__((ext_vector_type(8)));
typedef _Float16 half4 __attribute__((ext_vector_type(4)));
typedef float f32x4 __attribute__((ext_vector_type(4)));

#define NB 2
#define NS 2047
#define NC 1024
#define NN 2048
#define NH 16
#define ND 64

__device__ __forceinline__ void gl_lds16(const h16* g, h16* l) {
  __builtin_amdgcn_global_load_lds((const __attribute__((address_space(1))) void*)g,
                                   (__attribute__((address_space(3))) void*)l, 16, 0, 0);
}
__device__ __forceinline__ f32x4 mfma32(half8 a, half8 b, f32x4 c) {
  return __builtin_amdgcn_mfma_f32_16x16x32_f16(a, b, c, 0, 0, 0);
}
__device__ __forceinline__ f32x4 mfma16x(half4 a, half4 b, f32x4 c) {
  return __builtin_amdgcn_mfma_f32_16x16x16f16(a, b, c, 0, 0, 0);
}

// ---------- one fused cast kernel: xgh | w3h | wph contiguous ----------
__global__ __launch_bounds__(256) void cast_all_k(
    const float* __restrict__ x, const float* __restrict__ g,
    const float* __restrict__ qw, const float* __restrict__ pw, h16* __restrict__ out) {
  const size_t i = ((size_t)blockIdx.x * 256 + threadIdx.x) * 8;
  const float* src;
  if (i < (size_t)NB * NN * NC) {
    const int c = (int)(i & (NC - 1));
    const int n = (int)((i >> 10) & (NN - 1));
    const int b = (int)(i >> 21);
    src = (n == 0) ? (g + c) : (x + ((size_t)b * NS + (n - 1)) * NC + c);
  } else {
    const size_t j = i - (size_t)NB * NN * NC;
    src = (j < (size_t)3 * NC * NC) ? (qw + j) : (pw + (j - (size_t)3 * NC * NC));
  }
  float4 f0 = ((const float4*)src)[0];
  float4 f1 = ((const float4*)src)[1];
  h16 tmp[8];
  tmp[0] = (h16)f0.x; tmp[1] = (h16)f0.y; tmp[2] = (h16)f0.z; tmp[3] = (h16)f0.w;
  tmp[4] = (h16)f1.x; tmp[5] = (h16)f1.y; tmp[6] = (h16)f1.z; tmp[7] = (h16)f1.w;
  *(half8*)(out + i) = *(half8*)&tmp[0];
}

// ---------- QKV GEMM: 64x128 tile, BK=64, 2x2 wave grid, acc[2][4] ----------
// Occupancy fix (R7 PMC: Occ 14%, MfmaUtil 22%, latency-bound at 3 blocks/CU):
// BM 128->64 doubles grid to 1536 blocks (6/CU); LDS 24KB and acc[2][4]
// (~70 VGPR) allow all 6 resident (launch_bounds 256,6 = 24 waves/CU).
// Inner loop/staging identical to the R3-proven proj pattern.
__global__ __launch_bounds__(256, 6) void gemm_qkv_h(
    const h16* __restrict__ A, const h16* __restrict__ W,
    h16* __restrict__ qP, h16* __restrict__ kP, h16* __restrict__ vP) {
  __shared__ h16 SM[64 * 64 + 128 * 64];  // As(64x64) | Bs(128x64); V tile reuses [0,8192)
  h16* As = SM;
  h16* Bs = SM + 64 * 64;
  const int tid = threadIdx.x;
  // XCD-chunked bijective swizzle: 1536 blocks, 192/XCD chunk
  const int flat = blockIdx.y * 24 + blockIdx.x;
  const int swz = (flat & 7) * 192 + (flat >> 3);
  const int m0 = (swz / 24) * 64, j0 = (swz % 24) * 128;
  const int wid = tid >> 6, lane = tid & 63, l15 = lane & 15, quad = lane >> 4;
  const int wr = wid >> 1, wc = wid & 1;
  const int rl = lane >> 3, csw = (lane & 7) ^ rl;
  const h16* ag0 = A + (size_t)(m0 + wid * 16 + rl) * NC + csw * 8;
  const h16* ag1 = A + (size_t)(m0 + wid * 16 + 8 + rl) * NC + csw * 8;
  const h16* bg = W + (size_t)(j0 + wid * 32 + rl) * NC + csw * 8;
  f32x4 acc[2][4];
#pragma unroll
  for (int rt = 0; rt < 2; ++rt)
#pragma unroll
    for (int ct = 0; ct < 4; ++ct) acc[rt][ct] = (f32x4){0.f, 0.f, 0.f, 0.f};

  for (int k0 = 0; k0 < NC; k0 += 64) {
    __syncthreads();
    gl_lds16(ag0 + k0, &As[(wid * 16) * 64]);
    gl_lds16(ag1 + k0, &As[(wid * 16 + 8) * 64]);
#pragma unroll
    for (int i = 0; i < 4; ++i)
      gl_lds16(bg + (size_t)i * 8 * NC + k0, &Bs[(wid * 32 + i * 8) * 64]);
    __syncthreads();
#pragma unroll
    for (int ks = 0; ks < 2; ++ks) {
      const int p0 = ((ks * 4 + quad) ^ (l15 & 7)) * 8;
      half8 af[2], bf[4];
#pragma unroll
      for (int rt = 0; rt < 2; ++rt)
        af[rt] = *(const half8*)&As[(wr * 32 + rt * 16 + l15) * 64 + p0];
#pragma unroll
      for (int ct = 0; ct < 4; ++ct)
        bf[ct] = *(const half8*)&Bs[(wc * 64 + ct * 16 + l15) * 64 + p0];
#pragma unroll
      for (int rt = 0; rt < 2; ++rt)
#pragma unroll
        for (int ct = 0; ct < 4; ++ct)
          acc[rt][ct] = mfma32(af[rt], bf[ct], acc[rt][ct]);
    }
  }

  const int b = m0 >> 11, n0 = m0 & (NN - 1);
  if (j0 < 2 * NC) {
    // ---- Q or K: packed stores (head fixed per wave-column) ----
    h16* base = (j0 < NC) ? qP : kP;
    const int coff = (j0 < NC) ? 0 : NC;
    const int h = (j0 - coff + wc * 64) >> 6;
    h16* dst = base + ((size_t)(b * NH + h) * NN + n0) * ND;
#pragma unroll
    for (int rt = 0; rt < 2; ++rt)
#pragma unroll
      for (int ct = 0; ct < 4; ++ct)
#pragma unroll
        for (int r = 0; r < 4; ++r) {
          const int mloc = wr * 32 + rt * 16 + quad * 4 + r;
          dst[(size_t)mloc * ND + ct * 16 + l15] = (h16)acc[rt][ct][r];
        }
  } else {
    // ---- V: transpose 64(keys) x 128(2 heads x 64 d) through LDS ----
    __syncthreads();  // protect last K-step's LDS reads
#pragma unroll
    for (int rt = 0; rt < 2; ++rt)
#pragma unroll
      for (int ct = 0; ct < 4; ++ct)
#pragma unroll
        for (int r = 0; r < 4; ++r) {
          const int mloc = wr * 32 + rt * 16 + quad * 4 + r;   // key 0..63
          const int jloc = wc * 64 + ct * 16 + l15;            // col 0..127
          SM[mloc * 128 + (jloc ^ (((mloc >> 2) & 3) << 3))] = (h16)acc[rt][ct][r];
        }
    __syncthreads();
    const int kb0 = n0 >> 6;            // single key-block per tile
    const int h0 = (j0 - 2 * NC) >> 6;  // two heads per tile: h0, h0+1
    const int w = tid >> 6, d = tid & 63;
#pragma unroll
    for (int u = 0; u < 2; ++u) {
      const int bh = b * NH + h0 + u;
      h16 buf[16];
#pragma unroll
      for (int kk = 0; kk < 16; ++kk) {
        const int row = w * 16 + kk;
        buf[kk] = SM[row * 128 + ((u * 64 + d) ^ (((row >> 2) & 3) << 3))];
      }
      h16* dstv = vP + ((size_t)((bh * 32 + kb0) * 4 + w)) * 1024 + d * 16;
      *(half8*)dstv = *(half8*)&buf[0];
      *(half8*)(dstv + 8) = *(half8*)&buf[8];
    }
  }
}

// ---------- attention: key-split waves, direct global->VGPR K/V, no in-loop LDS ----------
__global__ __launch_bounds__(256, 3) void attn_h(
    const h16* __restrict__ qP, const h16* __restrict__ kP,
    const h16* __restrict__ vP, h16* __restrict__ outp) {
  __shared__ float RED[2 * 64 * 36];
  __shared__ float DEN[4 * 64];
  const int bx = blockIdx.x;
  const int qb = 31 - (bx >> 5);  // long q-blocks first
  const int bh = bx & 31;         // XCD-pinned: bh%8 == bx%8
  const int b = bh >> 4, h = bh & 15;
  const int tid = threadIdx.x, w = tid >> 6, lane = tid & 63;
  const int l15 = lane & 15, quad = lane >> 4;

  // Q B-frags from packed qP (dense 128B rows; scale folded)
  half8 bq[4][2];
#pragma unroll
  for (int nt = 0; nt < 4; ++nt) {
    const h16* qp = qP + ((size_t)bh * NN + qb * 64 + nt * 16 + l15) * ND + quad * 8;
    bq[nt][0] = (*(const half8*)qp) * (h16)0.125f;
    bq[nt][1] = (*(const half8*)(qp + 32)) * (h16)0.125f;
  }
  // dense per-lane fragment sources
  const h16* kbase = kP + ((size_t)bh * NN + w * 16 + l15) * ND + quad * 8;
  const h16* vbase = vP + ((size_t)bh * 32 * 4 + w) * 1024 + l15 * 16 + quad * 4;

  f32x4 o[4][4];
  float den[4] = {0.f, 0.f, 0.f, 0.f};
#pragma unroll
  for (int mt = 0; mt < 4; ++mt)
#pragma unroll
    for (int nt = 0; nt < 4; ++nt) o[mt][nt] = (f32x4){0.f, 0.f, 0.f, 0.f};

  half8 kf0 = *(const half8*)kbase;
  half8 kf1 = *(const half8*)(kbase + 32);
  half4 vf0 = *(const half4*)(vbase);
  half4 vf1 = *(const half4*)(vbase + 256);
  half4 vf2 = *(const half4*)(vbase + 512);
  half4 vf3 = *(const half4*)(vbase + 768);

  for (int kb = 0; kb <= qb; ++kb) {
    // register prefetch of next block (clamped re-read at tail: harmless)
    const int nkb = (kb < qb) ? kb + 1 : kb;
    const h16* kn = kbase + (size_t)nkb * 64 * ND;
    const h16* vn = vbase + (size_t)nkb * 4096;
    half8 nk0 = *(const half8*)kn;
    half8 nk1 = *(const half8*)(kn + 32);
    half4 nv0 = *(const half4*)(vn);
    half4 nv1 = *(const half4*)(vn + 256);
    half4 nv2 = *(const half4*)(vn + 512);
    half4 nv3 = *(const half4*)(vn + 768);
    __builtin_amdgcn_s_setprio(1);
#pragma unroll
    for (int nt = 0; nt < 4; ++nt) {
      f32x4 s = (f32x4){0.f, 0.f, 0.f, 0.f};
      s = mfma32(kf0, bq[nt][0], s);
      s = mfma32(kf1, bq[nt][1], s);
      float e0 = __expf(s[0]), e1 = __expf(s[1]);
      float e2 = __expf(s[2]), e3 = __expf(s[3]);
      den[nt] += (e0 + e1) + (e2 + e3);
      int2 pi;
      pi.x = __builtin_bit_cast(int, __builtin_amdgcn_cvt_pkrtz(e0, e1));
      pi.y = __builtin_bit_cast(int, __builtin_amdgcn_cvt_pkrtz(e2, e3));
      half4 p = __builtin_bit_cast(half4, pi);
      o[0][nt] = mfma16x(vf0, p, o[0][nt]);
      o[1][nt] = mfma16x(vf1, p, o[1][nt]);
      o[2][nt] = mfma16x(vf2, p, o[2][nt]);
      o[3][nt] = mfma16x(vf3, p, o[3][nt]);
    }
    __builtin_amdgcn_s_setprio(0);
    kf0 = nk0; kf1 = nk1;
    vf0 = nv0; vf1 = nv1; vf2 = nv2; vf3 = nv3;
  }

  // ---- epilogue: cross-wave reduction of O^T partials and den ----
#pragma unroll
  for (int nt = 0; nt < 4; ++nt) {
    den[nt] += __shfl_xor(den[nt], 16);
    den[nt] += __shfl_xor(den[nt], 32);
  }
  __syncthreads();
  if (quad == 0) {
#pragma unroll
    for (int nt = 0; nt < 4; ++nt) DEN[w * 64 + nt * 16 + l15] = den[nt];
  }
#pragma unroll
  for (int r = 0; r < 2; ++r) {  // d 0..31 then 32..63
    if (r) __syncthreads();
    if (w < 2) {
#pragma unroll
      for (int mt2 = 0; mt2 < 2; ++mt2)
#pragma unroll
        for (int nt = 0; nt < 4; ++nt)
          *(f32x4*)&RED[(w * 64 + nt * 16 + l15) * 36 + mt2 * 16 + quad * 4] =
              o[r * 2 + mt2][nt];
    }
    __syncthreads();
    if (w >= 2) {
#pragma unroll
      for (int mt2 = 0; mt2 < 2; ++mt2)
#pragma unroll
        for (int nt = 0; nt < 4; ++nt) {
          float* p = &RED[((w - 2) * 64 + nt * 16 + l15) * 36 + mt2 * 16 + quad * 4];
          f32x4 t = *(f32x4*)p;
          *(f32x4*)p = t + o[r * 2 + mt2][nt];
        }
    }
    __syncthreads();
    {
      const int q = w * 16 + l15;
      const float dt = DEN[q] + DEN[64 + q] + DEN[128 + q] + DEN[192 + q];
      const float inv = 1.f / dt;
      f32x4 x0 = *(const f32x4*)&RED[(0 * 64 + q) * 36 + quad * 8];
      f32x4 x1 = *(const f32x4*)&RED[(0 * 64 + q) * 36 + quad * 8 + 4];
      f32x4 y0 = *(const f32x4*)&RED[(1 * 64 + q) * 36 + quad * 8];
      f32x4 y1 = *(const f32x4*)&RED[(1 * 64 + q) * 36 + quad * 8 + 4];
      x0 += y0;
      x1 += y1;
      int4 pk;
      pk.x = __builtin_bit_cast(int, __builtin_amdgcn_cvt_pkrtz(x0[0] * inv, x0[1] * inv));
      pk.y = __builtin_bit_cast(int, __builtin_amdgcn_cvt_pkrtz(x0[2] * inv, x0[3] * inv));
      pk.z = __builtin_bit_cast(int, __builtin_amdgcn_cvt_pkrtz(x1[0] * inv, x1[1] * inv));
      pk.w = __builtin_bit_cast(int, __builtin_amdgcn_cvt_pkrtz(x1[2] * inv, x1[3] * inv));
      h16* op = outp + (size_t)(b * NN + qb * 64 + q) * NC + h * ND + r * 32 + quad * 8;
      *(half8*)op = __builtin_bit_cast(half8, pk);
    }
  }
}

// ---------- proj GEMM: 64x128, BK=64, 2x2 wave grid, acc[2][4]; +bias, fp32 out ----------
__global__ __launch_bounds__(256) void gemm_proj_h(
    const h16* __restrict__ Ah, const h16* __restrict__ W,
    const float* __restrict__ bias, float* __restrict__ out) {
  __shared__ h16 As[64 * 64];
  __shared__ h16 Bs[128 * 64];
  const int tid = threadIdx.x;
  const int flat = blockIdx.y * 8 + blockIdx.x;
  const int swz = (flat & 7) * 64 + (flat >> 3);
  const int m0 = (swz >> 3) * 64, j0 = (swz & 7) * 128;
  const int wid = tid >> 6, lane = tid & 63, l15 = lane & 15, quad = lane >> 4;
  const int wr = wid >> 1, wc = wid & 1;
  const int rl = lane >> 3, csw = (lane & 7) ^ rl;
  const h16* ag[2];
#pragma unroll
  for (int i = 0; i < 2; ++i) {
    int m = m0 + wid * 16 + i * 8 + rl;
    if (m > NB * NS - 1) m = NB * NS - 1;
    const int bb = (m >= NS) ? 1 : 0;
    ag[i] = Ah + (size_t)(bb * NN + m - bb * NS + 1) * NC + csw * 8;
  }
  const h16* bg = W + (size_t)(j0 + wid * 32 + rl) * NC + csw * 8;
  f32x4 acc[2][4];
#pragma unroll
  for (int rt = 0; rt < 2; ++rt)
#pragma unroll
    for (int ct = 0; ct < 4; ++ct) acc[rt][ct] = (f32x4){0.f, 0.f, 0.f, 0.f};

  for (int k0 = 0; k0 < NC; k0 += 64) {
    __syncthreads();
    gl_lds16(ag[0] + k0, &As[(wid * 16) * 64]);
    gl_lds16(ag[1] + k0, &As[(wid * 16 + 8) * 64]);
#pragma unroll
    for (int i = 0; i < 4; ++i)
      gl_lds16(bg + (size_t)i * 8 * NC + k0, &Bs[(wid * 32 + i * 8) * 64]);
    __syncthreads();
#pragma unroll
    for (int ks = 0; ks < 2; ++ks) {
      const int p0 = ((ks * 4 + quad) ^ (l15 & 7)) * 8;
      half8 af[2], bf[4];
#pragma unroll
      for (int rt = 0; rt < 2; ++rt)
        af[rt] = *(const half8*)&As[(wr * 32 + rt * 16 + l15) * 64 + p0];
#pragma unroll
      for (int ct = 0; ct < 4; ++ct)
        bf[ct] = *(const half8*)&Bs[(wc * 64 + ct * 16 + l15) * 64 + p0];
#pragma unroll
      for (int rt = 0; rt < 2; ++rt)
#pragma unroll
        for (int ct = 0; ct < 4; ++ct)
          acc[rt][ct] = mfma32(af[rt], bf[ct], acc[rt][ct]);
    }
  }
#pragma unroll
  for (int ct = 0; ct < 4; ++ct) {
    const float bv = bias[j0 + wc * 64 + ct * 16 + l15];
#pragma unroll
    for (int rt = 0; rt < 2; ++rt)
#pragma unroll
      for (int r = 0; r < 4; ++r) {
        const int mm = m0 + wr * 32 + rt * 16 + quad * 4 + r;
        if (mm < NB * NS)
          out[(size_t)mm * NC + j0 + wc * 64 + ct * 16 + l15] = acc[rt][ct][r] + bv;
      }
  }
}

extern "C" void kernel_launch(void* const* d_in, const int* in_sizes, int n_in,
                              void* d_out, int out_size, void* d_ws, size_t ws_size,
                              hipStream_t stream) {
  const float* x = (const float*)d_in[0];
  const float* g = (const float*)d_in[1];
  const float* qkv_w = (const float*)d_in[2];
  const float* proj_w = (const float*)d_in[3];
  const float* proj_b = (const float*)d_in[4];
  float* out = (float*)d_out;

  h16* xgh  = (h16*)d_ws;                        // NB*NN*NC     (contig with w3h|wph for cast)
  h16* w3h  = xgh + (size_t)NB * NN * NC;        // 3*NC*NC
  h16* wph  = w3h + (size_t)3 * NC * NC;         // NC*NC
  h16* qP   = wph + (size_t)NC * NC;             // NB*NH*NN*ND packed Q
  h16* kP   = qP + (size_t)NB * NH * NN * ND;    // packed K
  h16* vP   = kP + (size_t)NB * NH * NN * ND;    // packed V (transposed blocks)
  h16* attnh = vP + (size_t)NB * NH * NN * ND;   // attention out (h16)

  cast_all_k<<<dim3(4096), 256, 0, stream>>>(x, g, qkv_w, proj_w, xgh);
  gemm_qkv_h<<<dim3(24, 64), 256, 0, stream>>>(xgh, w3h, qP, kP, vP);
  attn_h<<<dim3(1024), 256, 0, stream>>>(qP, kP, vP, attnh);
  gemm_proj_h<<<dim3(8, 64), 256, 0, stream>>>(attnh, wph, proj_b, out);
}

// Round 9
// 169.788 us; speedup vs baseline: 1.0227x; 1.0227x over previous
//
#include <hip/hip_runtime.h>
#include <math.h>

typedef _Float16 h16;
typedef _Float16 half8 __attribute__((ext_vector_type(8)));
typedef _Float16 half4 __attribute__((ext_vector_type(4)));
typedef float f32x4 __attribute__((ext_vector_type(4)));

#define NB 2
#define NS 2047
#define NC 1024
#define NN 2048
#define NH 16
#define ND 64

__device__ __forceinline__ void gl_lds16(const h16* g, h16* l) {
  __builtin_amdgcn_global_load_lds((const __attribute__((address_space(1))) void*)g,
                                   (__attribute__((address_space(3))) void*)l, 16, 0, 0);
}
__device__ __forceinline__ f32x4 mfma32(half8 a, half8 b, f32x4 c) {
  return __builtin_amdgcn_mfma_f32_16x16x32_f16(a, b, c, 0, 0, 0);
}
__device__ __forceinline__ f32x4 mfma16x(half4 a, half4 b, f32x4 c) {
  return __builtin_amdgcn_mfma_f32_16x16x16f16(a, b, c, 0, 0, 0);
}

// ---------- one fused cast kernel: xgh | w3h | wph contiguous ----------
__global__ __launch_bounds__(256) void cast_all_k(
    const float* __restrict__ x, const float* __restrict__ g,
    const float* __restrict__ qw, const float* __restrict__ pw, h16* __restrict__ out) {
  const size_t i = ((size_t)blockIdx.x * 256 + threadIdx.x) * 8;
  const float* src;
  if (i < (size_t)NB * NN * NC) {
    const int c = (int)(i & (NC - 1));
    const int n = (int)((i >> 10) & (NN - 1));
    const int b = (int)(i >> 21);
    src = (n == 0) ? (g + c) : (x + ((size_t)b * NS + (n - 1)) * NC + c);
  } else {
    const size_t j = i - (size_t)NB * NN * NC;
    src = (j < (size_t)3 * NC * NC) ? (qw + j) : (pw + (j - (size_t)3 * NC * NC));
  }
  float4 f0 = ((const float4*)src)[0];
  float4 f1 = ((const float4*)src)[1];
  h16 tmp[8];
  tmp[0] = (h16)f0.x; tmp[1] = (h16)f0.y; tmp[2] = (h16)f0.z; tmp[3] = (h16)f0.w;
  tmp[4] = (h16)f1.x; tmp[5] = (h16)f1.y; tmp[6] = (h16)f1.z; tmp[7] = (h16)f1.w;
  *(half8*)(out + i) = *(half8*)&tmp[0];
}

// ---------- QKV GEMM: 256x256, BK=32, 8 waves (2Mx4N), 64KB STATIC LDS ----------
// Double-buffered, counted vmcnt(2) (never 0 in steady state), raw s_barrier.
// Paired-row granule swizzle: LDS [r2=row/2][gs=8 x 16B], granule gs holds
// global (row&1,kgran) = gs ^ (r2&7); swizzle applied on global SOURCE addr
// (linear LDS dest for global_load_lds), inverted on ds_read.
// R6 NaN root cause fixed: B read base is wn*2048 (32 row-pairs/wave), NOT
// wn*4096 (that was the A-side constant; wn>=1 read wrong/out-of-buffer data).
__global__ __launch_bounds__(512, 2) void gemm_qkv_h(
    const h16* __restrict__ A, const h16* __restrict__ W,
    h16* __restrict__ qP, h16* __restrict__ kP, h16* __restrict__ vP) {
  __shared__ h16 SM[32768];  // A:[2][128][64] | B:[2][128][64]  = 64KB
  const int tid = threadIdx.x;
  // XCD-chunked bijective swizzle over the 192-block grid (192 % 8 == 0)
  const int flat = blockIdx.y * 12 + blockIdx.x;
  const int swz = (flat & 7) * 24 + (flat >> 3);
  const int m0 = (swz / 12) * 256, j0 = (swz % 12) * 256;
  const int wid = tid >> 6, lane = tid & 63, l15 = lane & 15, quad = lane >> 4;
  const int wm = wid >> 2, wn = wid & 3;

  // staging source (pre-swizzled global address; LDS dest linear)
  const int glin = (lane & 7) ^ (lane >> 3);
  const int rowoff = glin >> 2, kg = glin & 3;
  const int srow = (wid * 8 + (lane >> 3)) * 2 + rowoff;  // tile-local row
  const h16* ag = A + (size_t)(m0 + srow) * NC + kg * 8;
  const h16* bg = W + (size_t)(j0 + srow) * NC + kg * 8;

  // read-side per-lane fragment bases (h16 offsets)
  const int rsw = l15 >> 1;
  const int gs = (((l15 & 1) << 2) | quad) ^ rsw;
  const int aoff = wm * 4096 + rsw * 64 + gs * 8;  // + fm*512 (128 rows = 64 r2/wave)
  const int boff = wn * 2048 + rsw * 64 + gs * 8;  // + fn*512 ( 64 rows = 32 r2/wave)

  f32x4 acc[8][4];
#pragma unroll
  for (int fm = 0; fm < 8; ++fm)
#pragma unroll
    for (int fn = 0; fn < 4; ++fn) acc[fm][fn] = (f32x4){0.f, 0.f, 0.f, 0.f};

  // prologue: stage tile 0 into buf0 (4 loads/thread in flight)
  gl_lds16(ag, &SM[(wid * 8) * 64]);
  gl_lds16(ag + (size_t)128 * NC, &SM[(64 + wid * 8) * 64]);
  gl_lds16(bg, &SM[16384 + (wid * 8) * 64]);
  gl_lds16(bg + (size_t)128 * NC, &SM[16384 + (64 + wid * 8) * 64]);

  for (int kt = 0; kt < 32; ++kt) {
    const int cur = kt & 1, nxt = cur ^ 1;
    const int k1 = (kt + 1) * 32;
    const bool pre = (kt < 31);
    const h16* Ab = SM + cur * 8192;
    const h16* Bb = SM + 16384 + cur * 8192;

    if (pre) {
      gl_lds16(ag + k1, &SM[nxt * 8192 + (wid * 8) * 64]);
      gl_lds16(ag + (size_t)128 * NC + k1, &SM[nxt * 8192 + (64 + wid * 8) * 64]);
      asm volatile("s_waitcnt vmcnt(2)" ::: "memory");
    } else {
      asm volatile("s_waitcnt vmcnt(0)" ::: "memory");
    }
    asm volatile("s_barrier" ::: "memory");

    half8 bf[4];
#pragma unroll
    for (int fn = 0; fn < 4; ++fn) bf[fn] = *(const half8*)&Bb[boff + fn * 512];

#pragma unroll
    for (int q = 0; q < 4; ++q) {
      if (q == 1 && pre)
        gl_lds16(bg + k1, &SM[16384 + nxt * 8192 + (wid * 8) * 64]);
      if (q == 2 && pre)
        gl_lds16(bg + (size_t)128 * NC + k1, &SM[16384 + nxt * 8192 + (64 + wid * 8) * 64]);
      half8 af0 = *(const half8*)&Ab[aoff + (q * 2 + 0) * 512];
      half8 af1 = *(const half8*)&Ab[aoff + (q * 2 + 1) * 512];
      __builtin_amdgcn_s_setprio(1);
#pragma unroll
      for (int fn = 0; fn < 4; ++fn) {
        acc[q * 2 + 0][fn] = mfma32(af0, bf[fn], acc[q * 2 + 0][fn]);
        acc[q * 2 + 1][fn] = mfma32(af1, bf[fn], acc[q * 2 + 1][fn]);
      }
      __builtin_amdgcn_s_setprio(0);
    }
    asm volatile("s_barrier" ::: "memory");
  }

  const int b = m0 >> 11, n0 = m0 & (NN - 1);
  if (j0 < 2 * NC) {
    // ---- Q or K: packed stores (quarter-wave 32B coalesced) ----
    h16* base = (j0 < NC) ? qP : kP;
    const int coff = (j0 < NC) ? 0 : NC;
    const int h = (j0 - coff + wn * 64) >> 6;  // fixed per wave
    h16* dst = base + ((size_t)(b * NH + h) * NN + n0) * ND;
#pragma unroll
    for (int fm = 0; fm < 8; ++fm)
#pragma unroll
      for (int fn = 0; fn < 4; ++fn)
#pragma unroll
        for (int r = 0; r < 4; ++r) {
          const int mloc = wm * 128 + fm * 16 + quad * 4 + r;
          dst[(size_t)mloc * ND + fn * 16 + l15] = (h16)acc[fm][fn][r];
        }
  } else {
    // ---- V: transpose 256 keys x 256 cols (4 heads) via LDS, two 128-row passes ----
    const int kb0 = n0 >> 6;            // 4 key-blocks per tile
    const int h0 = (j0 - 2 * NC) >> 6;  // 4 heads per tile
    const int g = tid >> 6, d = tid & 63;
    __syncthreads();  // all pipeline LDS traffic done before overwrite
#pragma unroll
    for (int p = 0; p < 2; ++p) {
      if (p) __syncthreads();
      if (wm == p) {
#pragma unroll
        for (int fm = 0; fm < 8; ++fm)
#pragma unroll
          for (int fn = 0; fn < 4; ++fn)
#pragma unroll
            for (int r = 0; r < 4; ++r) {
              const int lrow = fm * 16 + quad * 4 + r;          // 0..127
              const int col = wn * 64 + fn * 16 + l15;          // 0..255
              SM[lrow * 256 + (col ^ ((lrow & 7) << 3))] = (h16)acc[fm][fn][r];
            }
      }
      __syncthreads();
#pragma unroll
      for (int u = 0; u < 4; ++u) {
        const int idx = g * 4 + u;  // 0..31
        const int kbl2 = idx >> 4, hl = (idx >> 2) & 3, w4 = idx & 3;
        const int bh = b * NH + h0 + hl;
        h16 buf[16];
#pragma unroll
        for (int kk = 0; kk < 16; ++kk) {
          const int lrow = kbl2 * 64 + w4 * 16 + kk;
          buf[kk] = SM[lrow * 256 + ((hl * 64 + d) ^ ((lrow & 7) << 3))];
        }
        h16* dstv = vP + ((size_t)((bh * 32 + kb0 + p * 2 + kbl2) * 4 + w4)) * 1024 + d * 16;
        *(half8*)dstv = *(half8*)&buf[0];
        *(half8*)(dstv + 8) = *(half8*)&buf[8];
      }
    }
  }
}

// ---------- attention: key-split waves, direct global->VGPR K/V, no in-loop LDS ----------
__global__ __launch_bounds__(256, 3) void attn_h(
    const h16* __restrict__ qP, const h16* __restrict__ kP,
    const h16* __restrict__ vP, h16* __restrict__ outp) {
  __shared__ float RED[2 * 64 * 36];
  __shared__ float DEN[4 * 64];
  const int bx = blockIdx.x;
  const int qb = 31 - (bx >> 5);  // long q-blocks first
  const int bh = bx & 31;         // XCD-pinned: bh%8 == bx%8
  const int b = bh >> 4, h = bh & 15;
  const int tid = threadIdx.x, w = tid >> 6, lane = tid & 63;
  const int l15 = lane & 15, quad = lane >> 4;

  // Q B-frags from packed qP (dense 128B rows; scale folded)
  half8 bq[4][2];
#pragma unroll
  for (int nt = 0; nt < 4; ++nt) {
    const h16* qp = qP + ((size_t)bh * NN + qb * 64 + nt * 16 + l15) * ND + quad * 8;
    bq[nt][0] = (*(const half8*)qp) * (h16)0.125f;
    bq[nt][1] = (*(const half8*)(qp + 32)) * (h16)0.125f;
  }
  // dense per-lane fragment sources
  const h16* kbase = kP + ((size_t)bh * NN + w * 16 + l15) * ND + quad * 8;
  const h16* vbase = vP + ((size_t)bh * 32 * 4 + w) * 1024 + l15 * 16 + quad * 4;

  f32x4 o[4][4];
  float den[4] = {0.f, 0.f, 0.f, 0.f};
#pragma unroll
  for (int mt = 0; mt < 4; ++mt)
#pragma unroll
    for (int nt = 0; nt < 4; ++nt) o[mt][nt] = (f32x4){0.f, 0.f, 0.f, 0.f};

  half8 kf0 = *(const half8*)kbase;
  half8 kf1 = *(const half8*)(kbase + 32);
  half4 vf0 = *(const half4*)(vbase);
  half4 vf1 = *(const half4*)(vbase + 256);
  half4 vf2 = *(const half4*)(vbase + 512);
  half4 vf3 = *(const half4*)(vbase + 768);

  for (int kb = 0; kb <= qb; ++kb) {
    // register prefetch of next block (clamped re-read at tail: harmless)
    const int nkb = (kb < qb) ? kb + 1 : kb;
    const h16* kn = kbase + (size_t)nkb * 64 * ND;
    const h16* vn = vbase + (size_t)nkb * 4096;
    half8 nk0 = *(const half8*)kn;
    half8 nk1 = *(const half8*)(kn + 32);
    half4 nv0 = *(const half4*)(vn);
    half4 nv1 = *(const half4*)(vn + 256);
    half4 nv2 = *(const half4*)(vn + 512);
    half4 nv3 = *(const half4*)(vn + 768);
    __builtin_amdgcn_s_setprio(1);
#pragma unroll
    for (int nt = 0; nt < 4; ++nt) {
      f32x4 s = (f32x4){0.f, 0.f, 0.f, 0.f};
      s = mfma32(kf0, bq[nt][0], s);
      s = mfma32(kf1, bq[nt][1], s);
      float e0 = __expf(s[0]), e1 = __expf(s[1]);
      float e2 = __expf(s[2]), e3 = __expf(s[3]);
      den[nt] += (e0 + e1) + (e2 + e3);
      int2 pi;
      pi.x = __builtin_bit_cast(int, __builtin_amdgcn_cvt_pkrtz(e0, e1));
      pi.y = __builtin_bit_cast(int, __builtin_amdgcn_cvt_pkrtz(e2, e3));
      half4 p = __builtin_bit_cast(half4, pi);
      o[0][nt] = mfma16x(vf0, p, o[0][nt]);
      o[1][nt] = mfma16x(vf1, p, o[1][nt]);
      o[2][nt] = mfma16x(vf2, p, o[2][nt]);
      o[3][nt] = mfma16x(vf3, p, o[3][nt]);
    }
    __builtin_amdgcn_s_setprio(0);
    kf0 = nk0; kf1 = nk1;
    vf0 = nv0; vf1 = nv1; vf2 = nv2; vf3 = nv3;
  }

  // ---- epilogue: cross-wave reduction of O^T partials and den ----
#pragma unroll
  for (int nt = 0; nt < 4; ++nt) {
    den[nt] += __shfl_xor(den[nt], 16);
    den[nt] += __shfl_xor(den[nt], 32);
  }
  __syncthreads();
  if (quad == 0) {
#pragma unroll
    for (int nt = 0; nt < 4; ++nt) DEN[w * 64 + nt * 16 + l15] = den[nt];
  }
#pragma unroll
  for (int r = 0; r < 2; ++r) {  // d 0..31 then 32..63
    if (r) __syncthreads();
    if (w < 2) {
#pragma unroll
      for (int mt2 = 0; mt2 < 2; ++mt2)
#pragma unroll
        for (int nt = 0; nt < 4; ++nt)
          *(f32x4*)&RED[(w * 64 + nt * 16 + l15) * 36 + mt2 * 16 + quad * 4] =
              o[r * 2 + mt2][nt];
    }
    __syncthreads();
    if (w >= 2) {
#pragma unroll
      for (int mt2 = 0; mt2 < 2; ++mt2)
#pragma unroll
        for (int nt = 0; nt < 4; ++nt) {
          float* p = &RED[((w - 2) * 64 + nt * 16 + l15) * 36 + mt2 * 16 + quad * 4];
          f32x4 t = *(f32x4*)p;
          *(f32x4*)p = t + o[r * 2 + mt2][nt];
        }
    }
    __syncthreads();
    {
      const int q = w * 16 + l15;
      const float dt = DEN[q] + DEN[64 + q] + DEN[128 + q] + DEN[192 + q];
      const float inv = 1.f / dt;
      f32x4 x0 = *(const f32x4*)&RED[(0 * 64 + q) * 36 + quad * 8];
      f32x4 x1 = *(const f32x4*)&RED[(0 * 64 + q) * 36 + quad * 8 + 4];
      f32x4 y0 = *(const f32x4*)&RED[(1 * 64 + q) * 36 + quad * 8];
      f32x4 y1 = *(const f32x4*)&RED[(1 * 64 + q) * 36 + quad * 8 + 4];
      x0 += y0;
      x1 += y1;
      int4 pk;
      pk.x = __builtin_bit_cast(int, __builtin_amdgcn_cvt_pkrtz(x0[0] * inv, x0[1] * inv));
      pk.y = __builtin_bit_cast(int, __builtin_amdgcn_cvt_pkrtz(x0[2] * inv, x0[3] * inv));
      pk.z = __builtin_bit_cast(int, __builtin_amdgcn_cvt_pkrtz(x1[0] * inv, x1[1] * inv));
      pk.w = __builtin_bit_cast(int, __builtin_amdgcn_cvt_pkrtz(x1[2] * inv, x1[3] * inv));
      h16* op = outp + (size_t)(b * NN + qb * 64 + q) * NC + h * ND + r * 32 + quad * 8;
      *(half8*)op = __builtin_bit_cast(half8, pk);
    }
  }
}

// ---------- proj GEMM: 64x128, BK=64, 2x2 wave grid, acc[2][4]; +bias, fp32 out ----------
__global__ __launch_bounds__(256) void gemm_proj_h(
    const h16* __restrict__ Ah, const h16* __restrict__ W,
    const float* __restrict__ bias, float* __restrict__ out) {
  __shared__ h16 As[64 * 64];
  __shared__ h16 Bs[128 * 64];
  const int tid = threadIdx.x;
  const int flat = blockIdx.y * 8 + blockIdx.x;
  const int swz = (flat & 7) * 64 + (flat >> 3);
  const int m0 = (swz >> 3) * 64, j0 = (swz & 7) * 128;
  const int wid = tid >> 6, lane = tid & 63, l15 = lane & 15, quad = lane >> 4;
  const int wr = wid >> 1, wc = wid & 1;
  const int rl = lane >> 3, csw = (lane & 7) ^ rl;
  const h16* ag[2];
#pragma unroll
  for (int i = 0; i < 2; ++i) {
    int m = m0 + wid * 16 + i * 8 + rl;
    if (m > NB * NS - 1) m = NB * NS - 1;
    const int bb = (m >= NS) ? 1 : 0;
    ag[i] = Ah + (size_t)(bb * NN + m - bb * NS + 1) * NC + csw * 8;
  }
  const h16* bg = W + (size_t)(j0 + wid * 32 + rl) * NC + csw * 8;
  f32x4 acc[2][4];
#pragma unroll
  for (int rt = 0; rt < 2; ++rt)
#pragma unroll
    for (int ct = 0; ct < 4; ++ct) acc[rt][ct] = (f32x4){0.f, 0.f, 0.f, 0.f};

  for (int k0 = 0; k0 < NC; k0 += 64) {
    __syncthreads();
    gl_lds16(ag[0] + k0, &As[(wid * 16) * 64]);
    gl_lds16(ag[1] + k0, &As[(wid * 16 + 8) * 64]);
#pragma unroll
    for (int i = 0; i < 4; ++i)
      gl_lds16(bg + (size_t)i * 8 * NC + k0, &Bs[(wid * 32 + i * 8) * 64]);
    __syncthreads();
#pragma unroll
    for (int ks = 0; ks < 2; ++ks) {
      const int p0 = ((ks * 4 + quad) ^ (l15 & 7)) * 8;
      half8 af[2], bf[4];
#pragma unroll
      for (int rt = 0; rt < 2; ++rt)
        af[rt] = *(const half8*)&As[(wr * 32 + rt * 16 + l15) * 64 + p0];
#pragma unroll
      for (int ct = 0; ct < 4; ++ct)
        bf[ct] = *(const half8*)&Bs[(wc * 64 + ct * 16 + l15) * 64 + p0];
#pragma unroll
      for (int rt = 0; rt < 2; ++rt)
#pragma unroll
        for (int ct = 0; ct < 4; ++ct)
          acc[rt][ct] = mfma32(af[rt], bf[ct], acc[rt][ct]);
    }
  }
#pragma unroll
  for (int ct = 0; ct < 4; ++ct) {
    const float bv = bias[j0 + wc * 64 + ct * 16 + l15];
#pragma unroll
    for (int rt = 0; rt < 2; ++rt)
#pragma unroll
      for (int r = 0; r < 4; ++r) {
        const int mm = m0 + wr * 32 + rt * 16 + quad * 4 + r;
        if (mm < NB * NS)
          out[(size_t)mm * NC + j0 + wc * 64 + ct * 16 + l15] = acc[rt][ct][r] + bv;
      }
  }
}

extern "C" void kernel_launch(void* const* d_in, const int* in_sizes, int n_in,
                              void* d_out, int out_size, void* d_ws, size_t ws_size,
                              hipStream_t stream) {
  const float* x = (const float*)d_in[0];
  const float* g = (const float*)d_in[1];
  const float* qkv_w = (const float*)d_in[2];
  const float* proj_w = (const float*)d_in[3];
  const float* proj_b = (const float*)d_in[4];
  float* out = (float*)d_out;

  h16* xgh  = (h16*)d_ws;                        // NB*NN*NC     (contig with w3h|wph for cast)
  h16* w3h  = xgh + (size_t)NB * NN * NC;        // 3*NC*NC
  h16* wph  = w3h + (size_t)3 * NC * NC;         // NC*NC
  h16* qP   = wph + (size_t)NC * NC;             // NB*NH*NN*ND packed Q
  h16* kP   = qP + (size_t)NB * NH * NN * ND;    // packed K
  h16* vP   = kP + (size_t)NB * NH * NN * ND;    // packed V (transposed blocks)
  h16* attnh = vP + (size_t)NB * NH * NN * ND;   // attention out (h16)

  cast_all_k<<<dim3(4096), 256, 0, stream>>>(x, g, qkv_w, proj_w, xgh);
  gemm_qkv_h<<<dim3(12, 16), 512, 0, stream>>>(xgh, w3h, qP, kP, vP);
  attn_h<<<dim3(1024), 256, 0, stream>>>(qP, kP, vP, attnh);
  gemm_proj_h<<<dim3(8, 64), 256, 0, stream>>>(attnh, wph, proj_b, out);
}